// Round 1
// baseline (1313.071 us; speedup 1.0000x reference)
//
#include <hip/hip_runtime.h>
#include <math.h>

// Problem constants
constexpr int IND0 = 512;   // input dim
constexpr int HID  = 256;   // hidden dim
constexpr int NB   = 16;    // batch
constexpr int NS   = 512;   // phoneme positions
constexpr int NT   = 4096;  // padded frames (S * DUR_MAX)

// ---------------------------------------------------------------------------
// Weight transpose: src (256, IND, 3) row-major -> dst[(ko*IND + i)*256 + o]
// so the GEMM can stage coalesced [BK][256] tiles.
__global__ void transpose_w_kernel(const float* __restrict__ src,
                                   float* __restrict__ dst, int IND) {
    int total = IND * 3 * 256;
    for (int idx = blockIdx.x * blockDim.x + threadIdx.x; idx < total;
         idx += gridDim.x * blockDim.x) {
        int o  = idx & 255;
        int q  = idx >> 8;
        int ko = q / IND;
        int i  = q - ko * IND;
        dst[idx] = src[(o * IND + i) * 3 + ko];
    }
}

// ---------------------------------------------------------------------------
// Per-batch inclusive cumsum of durations (S=512). One wave per batch.
__global__ void cumsum_kernel(const int* __restrict__ dur, int* __restrict__ cum) {
    int b = blockIdx.x;
    int lane = threadIdx.x;            // 0..63
    int base = b * NS + lane * 8;
    int v[8];
    int s = 0;
    #pragma unroll
    for (int j = 0; j < 8; ++j) { v[j] = dur[base + j]; s += v[j]; }
    int incl = s;
    for (int off = 1; off < 64; off <<= 1) {
        int n = __shfl_up(incl, off, 64);
        if (lane >= off) incl += n;
    }
    int run = incl - s;                // exclusive offset for this lane
    #pragma unroll
    for (int j = 0; j < 8; ++j) { run += v[j]; cum[base + j] = run; }
}

// ---------------------------------------------------------------------------
// Length regulator: up[b,t,:] = emb[b, idx(b,t), :] if t < cum[-1] else 0
// 2 rows per 256-thread block; 128 lanes x float4 per row (512 floats).
__global__ void regulator_kernel(const float* __restrict__ emb,
                                 const int* __restrict__ cum,
                                 float* __restrict__ up) {
    int tid = threadIdx.x;
    int row = blockIdx.x * 2 + (tid >> 7);
    int j = tid & 127;
    int b = row >> 12;            // / 4096
    int t = row & (NT - 1);
    const int* c = cum + b * NS;
    int total = c[NS - 1];
    float4 val = make_float4(0.f, 0.f, 0.f, 0.f);
    if (t < total) {
        int lo = 0, hi = NS;      // first idx with c[idx] > t
        while (lo < hi) {
            int mid = (lo + hi) >> 1;
            if (c[mid] <= t) lo = mid + 1; else hi = mid;
        }
        int idx = lo < NS ? lo : NS - 1;
        val = ((const float4*)(emb + ((size_t)b * NS + idx) * IND0))[j];
    }
    ((float4*)(up + ((size_t)b * NT + t) * IND0))[j] = val;
}

// ---------------------------------------------------------------------------
// Fused conv1d(k=3, pad=1) + bias + relu + LayerNorm(channels) [+ optional
// fused 1x1 head]. Implicit im2col GEMM: rows m = (b, s), cols = 256 out
// channels, K = IND*3. Block: 32 rows x 256 cols, 256 threads, 4x8 reg tile.
// FIN: 0 = write normalized h to hout; 1 = dur head (exp, max 1); 2 = f0 head.
template<int IND, int FIN>
__global__ __launch_bounds__(256)
void conv_ln_kernel(const float* __restrict__ x, int SL,
                    const float* __restrict__ Wt, const float* __restrict__ bias,
                    const float* __restrict__ gamma, const float* __restrict__ beta,
                    float* __restrict__ hout,
                    const float* __restrict__ wfin, const float* __restrict__ bfin,
                    float* __restrict__ fout) {
    constexpr int K = IND * 3;
    __shared__ float a_lds[32][16];
    __shared__ float w_lds[16 * 256];
    __shared__ float h_lds[32][257];

    int tid = threadIdx.x;
    int m0 = blockIdx.x * 32;
    int tm = tid >> 5;                 // 0..7
    int tn = tid & 31;                 // 0..31

    float acc[4][8];
    #pragma unroll
    for (int mi = 0; mi < 4; ++mi)
        #pragma unroll
        for (int ni = 0; ni < 8; ++ni) acc[mi][ni] = 0.f;

    for (int k0 = 0; k0 < K; k0 += 16) {
        __syncthreads();
        // --- stage A tile (32 x 16), float4, zero-padded at time boundaries
        if (tid < 128) {
            int fm = tid >> 2, kf = tid & 3;
            int m = m0 + fm;
            int b = m / SL, s = m - b * SL;
            int ko = k0 / IND, i0 = k0 - ko * IND;
            int srow = s + ko - 1;
            float4 v = make_float4(0.f, 0.f, 0.f, 0.f);
            if (srow >= 0 && srow < SL)
                v = *(const float4*)(x + ((size_t)b * SL + srow) * IND + i0 + kf * 4);
            *(float4*)(&a_lds[fm][kf * 4]) = v;
        }
        // --- stage W tile (16 x 256), float4, coalesced
        #pragma unroll
        for (int t = 0; t < 4; ++t) {
            int kk = t * 4 + (tid >> 6);
            int o = (tid & 63) * 4;
            float4 v = *(const float4*)(Wt + (size_t)(k0 + kk) * 256 + o);
            *(float4*)(&w_lds[kk * 256 + o]) = v;
        }
        __syncthreads();
        #pragma unroll
        for (int kk = 0; kk < 16; ++kk) {
            float a[4];
            #pragma unroll
            for (int mi = 0; mi < 4; ++mi) a[mi] = a_lds[tm * 4 + mi][kk];
            #pragma unroll
            for (int ni = 0; ni < 8; ++ni) {
                float w = w_lds[kk * 256 + tn + 32 * ni];
                #pragma unroll
                for (int mi = 0; mi < 4; ++mi)
                    acc[mi][ni] = fmaf(a[mi], w, acc[mi][ni]);
            }
        }
    }
    __syncthreads();

    // bias + relu -> LDS tile
    #pragma unroll
    for (int ni = 0; ni < 8; ++ni) {
        int c = tn + 32 * ni;
        float bv = bias[c];
        #pragma unroll
        for (int mi = 0; mi < 4; ++mi) {
            float v = acc[mi][ni] + bv;
            h_lds[tm * 4 + mi][c] = v > 0.f ? v : 0.f;
        }
    }
    __syncthreads();

    // LayerNorm over 256 channels; 8 lanes per row
    int row = tid >> 3, j = tid & 7;
    float sum = 0.f, sq = 0.f;
    #pragma unroll
    for (int cc = 0; cc < 32; ++cc) {
        float v = h_lds[row][j + 8 * cc];
        sum += v; sq += v * v;
    }
    #pragma unroll
    for (int off = 4; off >= 1; off >>= 1) {
        sum += __shfl_xor(sum, off, 8);
        sq  += __shfl_xor(sq,  off, 8);
    }
    float mean = sum * (1.f / 256.f);
    float var  = sq * (1.f / 256.f) - mean * mean;
    float rs   = rsqrtf(var + 1e-5f);
    int m = m0 + row;

    if (FIN == 0) {
        #pragma unroll
        for (int cc = 0; cc < 32; ++cc) {
            int c = j + 8 * cc;
            float v = (h_lds[row][c] - mean) * rs * gamma[c] + beta[c];
            hout[(size_t)m * 256 + c] = v;
        }
    } else {
        float part = 0.f;
        #pragma unroll
        for (int cc = 0; cc < 32; ++cc) {
            int c = j + 8 * cc;
            float v = (h_lds[row][c] - mean) * rs * gamma[c] + beta[c];
            part += v * wfin[c];
        }
        #pragma unroll
        for (int off = 4; off >= 1; off >>= 1) part += __shfl_xor(part, off, 8);
        if (j == 0) {
            float r = part + bfin[0];
            if (FIN == 1) { r = expf(r); r = r > 1.f ? r : 1.f; }
            fout[m] = r;
        }
    }
}

// ---------------------------------------------------------------------------
extern "C" void kernel_launch(void* const* d_in, const int* in_sizes, int n_in,
                              void* d_out, int out_size, void* d_ws, size_t ws_size,
                              hipStream_t stream) {
    const float* emb    = (const float*)d_in[0];
    const int*   dur    = (const int*)  d_in[1];
    const float* dp_w1  = (const float*)d_in[2];
    const float* dp_b1  = (const float*)d_in[3];
    const float* dp_g1  = (const float*)d_in[4];
    const float* dp_be1 = (const float*)d_in[5];
    const float* dp_w2  = (const float*)d_in[6];
    const float* dp_b2  = (const float*)d_in[7];
    const float* dp_g2  = (const float*)d_in[8];
    const float* dp_be2 = (const float*)d_in[9];
    const float* dp_w3  = (const float*)d_in[10];
    const float* dp_b3  = (const float*)d_in[11];
    const float* f0_w1  = (const float*)d_in[12];
    const float* f0_b1  = (const float*)d_in[13];
    const float* f0_g1  = (const float*)d_in[14];
    const float* f0_be1 = (const float*)d_in[15];
    const float* f0_w2  = (const float*)d_in[16];
    const float* f0_b2  = (const float*)d_in[17];

    float* up   = (float*)d_out;                       // (16, 4096, 512)
    float* pdur = up + (size_t)NB * NT * IND0;         // (16, 512)
    float* pf0  = pdur + NB * NS;                      // (16, 4096)

    char* ws = (char*)d_ws;
    int*   cum = (int*)ws;                                       // 32 KB
    float* Wt1 = (float*)(ws + 32768);                           // 1536x256
    float* Wt2 = (float*)(ws + 32768 + 1572864);                 // 768x256
    float* Wtf = (float*)(ws + 32768 + 1572864 + 786432);        // 1536x256
    float* h1  = (float*)(ws + 32768 + 1572864 + 786432 + 1572864); // 8 MB

    transpose_w_kernel<<<512, 256, 0, stream>>>(dp_w1, Wt1, 512);
    transpose_w_kernel<<<512, 256, 0, stream>>>(dp_w2, Wt2, 256);
    transpose_w_kernel<<<512, 256, 0, stream>>>(f0_w1, Wtf, 512);
    cumsum_kernel<<<NB, 64, 0, stream>>>(dur, cum);
    regulator_kernel<<<NB * NT / 2, 256, 0, stream>>>(emb, cum, up);

    // duration predictor
    conv_ln_kernel<512, 0><<<NB * NS / 32, 256, 0, stream>>>(
        emb, NS, Wt1, dp_b1, dp_g1, dp_be1, h1, nullptr, nullptr, nullptr);
    conv_ln_kernel<256, 1><<<NB * NS / 32, 256, 0, stream>>>(
        h1, NS, Wt2, dp_b2, dp_g2, dp_be2, nullptr, dp_w3, dp_b3, pdur);
    // f0 predictor on upsampled embeddings (reads d_out region 0)
    conv_ln_kernel<512, 2><<<NB * NT / 32, 256, 0, stream>>>(
        up, NT, Wtf, f0_b1, f0_g1, f0_be1, nullptr, f0_w2, f0_b2, pf0);
}

// Round 2
// 266.338 us; speedup vs baseline: 4.9301x; 4.9301x over previous
//
#include <hip/hip_runtime.h>
#include <math.h>

typedef __attribute__((ext_vector_type(8))) short short8;
typedef __attribute__((ext_vector_type(4))) float f32x4;
typedef __attribute__((ext_vector_type(4))) unsigned short us4;

constexpr int NB = 16, NS = 512, NT = 4096, IND0 = 512, HID = 256;

__device__ __forceinline__ unsigned short f2bf(float f) {
    __bf16 h = (__bf16)f;
    return __builtin_bit_cast(unsigned short, h);
}
__device__ __forceinline__ float bf2f(unsigned short h) {
    return __uint_as_float(((unsigned)h) << 16);
}

// ---------------------------------------------------------------------------
// Weight transpose+cast: src (256, IND, 3) f32 -> dst[n*K + ko*IND + i] bf16
__global__ void wprep_kernel(const float* __restrict__ src,
                             unsigned short* __restrict__ dst, int IND) {
    int K = 3 * IND;
    int total = 256 * K;
    for (int idx = blockIdx.x * blockDim.x + threadIdx.x; idx < total;
         idx += gridDim.x * blockDim.x) {
        int n = idx / K;
        int rem = idx - n * K;
        int ko = rem / IND;
        int i = rem - ko * IND;
        dst[idx] = f2bf(src[(n * IND + i) * 3 + ko]);
    }
}

// ---------------------------------------------------------------------------
// Per-batch inclusive cumsum of durations (S=512). One wave per batch.
__global__ void cumsum_kernel(const int* __restrict__ dur, int* __restrict__ cum) {
    int b = blockIdx.x;
    int lane = threadIdx.x;  // 0..63
    int base = b * NS + lane * 8;
    int v[8];
    int s = 0;
    #pragma unroll
    for (int j = 0; j < 8; ++j) { v[j] = dur[base + j]; s += v[j]; }
    int incl = s;
    for (int off = 1; off < 64; off <<= 1) {
        int n = __shfl_up(incl, off, 64);
        if (lane >= off) incl += n;
    }
    int run = incl - s;
    #pragma unroll
    for (int j = 0; j < 8; ++j) { run += v[j]; cum[base + j] = run; }
}

// ---------------------------------------------------------------------------
// Length regulator: writes fp32 up (output 0) AND idx table for the f0 conv.
__global__ void regulator_kernel(const float* __restrict__ emb,
                                 const int* __restrict__ cum,
                                 float* __restrict__ up,
                                 int* __restrict__ idxarr) {
    int tid = threadIdx.x;
    int row = blockIdx.x * 2 + (tid >> 7);
    int j = tid & 127;
    int b = row >> 12;
    int t = row & (NT - 1);
    const int* c = cum + b * NS;
    int total = c[NS - 1];
    float4 val = make_float4(0.f, 0.f, 0.f, 0.f);
    int idx = -1;
    if (t < total) {
        int lo = 0, hi = NS;  // first idx with c[idx] > t
        while (lo < hi) {
            int mid = (lo + hi) >> 1;
            if (c[mid] <= t) lo = mid + 1; else hi = mid;
        }
        idx = lo < NS ? lo : NS - 1;
        val = ((const float4*)(emb + ((size_t)b * NS + idx) * IND0))[j];
    }
    ((float4*)(up + ((size_t)b * NT + t) * IND0))[j] = val;
    if (j == 0) idxarr[b * NT + t] = idx;
}

// ---------------------------------------------------------------------------
// Fused conv1d(k=3,pad=1) + bias + relu + LayerNorm(256 ch) [+ fused 1x1 head]
// as implicit-im2col bf16 MFMA GEMM. Block: 128 rows x 256 cols, 256 threads
// (4 waves), wave tile 128x64. BK=32, single LDS buffer, prefetch-into-regs.
// MODE: 0 = direct f32 rows (emb), 1 = gather f32 rows via idxarr (emb+idx),
//       2 = direct bf16 rows (h1).
// FIN:  0 = write normalized bf16 to hout; 1 = dur head (exp,max1); 2 = f0 head.
template<int MODE, int IND, int FIN, int LOGSL>
__global__ __launch_bounds__(256)
void conv_mfma(const void* __restrict__ srcv, const int* __restrict__ idxarr,
               const unsigned short* __restrict__ Wt,   // [256][K] bf16
               const float* __restrict__ bias, const float* __restrict__ gamma,
               const float* __restrict__ beta, unsigned short* __restrict__ hout,
               const float* __restrict__ wfin, const float* __restrict__ bfin,
               float* __restrict__ fout) {
    constexpr int K = 3 * IND;
    constexpr int NSTEP = K / 32;
    constexpr int LOGIND = (IND == 512) ? 9 : 8;
    constexpr int SL = 1 << LOGSL;

    __shared__ unsigned short smem[32768];  // 64 KB
    unsigned short* Alds = smem;            // [128][40] -> 5120 ushorts
    unsigned short* Blds = smem + 5120;     // [256][40] -> 10240 ushorts

    const int t = threadIdx.x;
    const int m0 = blockIdx.x * 128;
    const int w = t >> 6, l = t & 63, llo = l & 15, lhi = l >> 4;

    // A-staging: thread covers row=t>>1, half=t&1 (16 elems)
    const int arow = t >> 1, ahalf = t & 1;
    const int am = m0 + arow;
    const int ab = am >> LOGSL;
    const int as_ = am & (SL - 1);

    f32x4 acc[8][4];
    #pragma unroll
    for (int i = 0; i < 8; ++i)
        #pragma unroll
        for (int j = 0; j < 4; ++j) acc[i][j] = (f32x4){0.f, 0.f, 0.f, 0.f};

    short8 a0, a1, bsr[4];
    const float* srcf = (const float*)srcv;
    const unsigned short* srch = (const unsigned short*)srcv;

    auto loadA = [&](int st) {
        int k0 = st * 32;
        int ko = k0 >> LOGIND;
        int i0 = (k0 & (IND - 1)) + ahalf * 16;
        int tr = as_ + ko - 1;
        bool valid = (tr >= 0) && (tr < SL);
        long srow = 0;
        if (MODE == 1) {
            if (valid) {
                int ix = idxarr[(ab << LOGSL) + tr];
                if (ix < 0) valid = false;
                else srow = (long)ab * NS + ix;
            }
        } else {
            srow = (long)ab * SL + tr;
        }
        if (MODE == 2) {
            if (valid) {
                const unsigned short* p = srch + srow * IND + i0;
                a0 = *(const short8*)p;
                a1 = *(const short8*)(p + 8);
            } else {
                a0 = short8{0,0,0,0,0,0,0,0};
                a1 = short8{0,0,0,0,0,0,0,0};
            }
        } else {
            float4 v0, v1, v2, v3;
            if (valid) {
                const float4* p = (const float4*)(srcf + srow * IND + i0);
                v0 = p[0]; v1 = p[1]; v2 = p[2]; v3 = p[3];
            } else {
                v0 = v1 = v2 = v3 = make_float4(0.f, 0.f, 0.f, 0.f);
            }
            short8 x0, x1;
            x0[0] = (short)f2bf(v0.x); x0[1] = (short)f2bf(v0.y);
            x0[2] = (short)f2bf(v0.z); x0[3] = (short)f2bf(v0.w);
            x0[4] = (short)f2bf(v1.x); x0[5] = (short)f2bf(v1.y);
            x0[6] = (short)f2bf(v1.z); x0[7] = (short)f2bf(v1.w);
            x1[0] = (short)f2bf(v2.x); x1[1] = (short)f2bf(v2.y);
            x1[2] = (short)f2bf(v2.z); x1[3] = (short)f2bf(v2.w);
            x1[4] = (short)f2bf(v3.x); x1[5] = (short)f2bf(v3.y);
            x1[6] = (short)f2bf(v3.z); x1[7] = (short)f2bf(v3.w);
            a0 = x0; a1 = x1;
        }
    };
    auto loadB = [&](int st) {
        int k0 = st * 32;
        #pragma unroll
        for (int p = 0; p < 4; ++p) {
            int cidx = p * 256 + t;
            int n = cidx >> 2, ch = cidx & 3;
            bsr[p] = *(const short8*)(Wt + (size_t)n * K + k0 + ch * 8);
        }
    };
    auto writeAB = [&]() {
        *(short8*)&Alds[arow * 40 + ahalf * 16] = a0;
        *(short8*)&Alds[arow * 40 + ahalf * 16 + 8] = a1;
        #pragma unroll
        for (int p = 0; p < 4; ++p) {
            int cidx = p * 256 + t;
            int n = cidx >> 2, ch = cidx & 3;
            *(short8*)&Blds[n * 40 + ch * 8] = bsr[p];
        }
    };

    loadA(0); loadB(0);
    writeAB();
    __syncthreads();
    for (int st = 0; st < NSTEP; ++st) {
        bool more = (st + 1 < NSTEP);
        if (more) { loadA(st + 1); loadB(st + 1); }
        short8 af[8], bfr[4];
        #pragma unroll
        for (int mf = 0; mf < 8; ++mf)
            af[mf] = *(const short8*)&Alds[(mf * 16 + llo) * 40 + lhi * 8];
        #pragma unroll
        for (int nf = 0; nf < 4; ++nf)
            bfr[nf] = *(const short8*)&Blds[(w * 64 + nf * 16 + llo) * 40 + lhi * 8];
        #pragma unroll
        for (int mf = 0; mf < 8; ++mf)
            #pragma unroll
            for (int nf = 0; nf < 4; ++nf)
                acc[mf][nf] = __builtin_amdgcn_mfma_f32_16x16x32_bf16(
                    af[mf], bfr[nf], acc[mf][nf], 0, 0, 0);
        __syncthreads();
        if (more) writeAB();
        __syncthreads();
    }

    // Epilogue: bias + relu -> H (XOR-swizzled [128][256] bf16 over whole smem)
    unsigned short* H = smem;
    #pragma unroll
    for (int nf = 0; nf < 4; ++nf) {
        int col = w * 64 + nf * 16 + llo;
        float bv = bias[col];
        #pragma unroll
        for (int mf = 0; mf < 8; ++mf)
            #pragma unroll
            for (int r = 0; r < 4; ++r) {
                int row = mf * 16 + lhi * 4 + r;
                float v = acc[mf][nf][r] + bv;
                v = v > 0.f ? v : 0.f;
                H[row * 256 + ((((col >> 2) ^ (row & 15)) << 2) | (col & 3))] = f2bf(v);
            }
    }
    __syncthreads();

    // LayerNorm over 256 channels: 2 threads/row, 128 cols each.
    int row = t >> 1, jj = t & 1;
    const unsigned short* Hr = H + row * 256;
    int rx = row & 15;
    float sum = 0.f, sq = 0.f;
    #pragma unroll
    for (int c4 = 0; c4 < 32; ++c4) {
        int g = jj * 32 + c4;
        us4 hv = *(const us4*)&Hr[((g ^ rx) << 2)];
        #pragma unroll
        for (int e = 0; e < 4; ++e) { float f = bf2f(hv[e]); sum += f; sq += f * f; }
    }
    sum += __shfl_xor(sum, 1);
    sq  += __shfl_xor(sq, 1);
    float mean = sum * (1.f / 256.f);
    float var  = sq * (1.f / 256.f) - mean * mean;
    float rs   = rsqrtf(var + 1e-5f);
    int m = m0 + row;

    if (FIN == 0) {
        #pragma unroll
        for (int c4 = 0; c4 < 32; ++c4) {
            int g = jj * 32 + c4;
            us4 hv = *(const us4*)&Hr[((g ^ rx) << 2)];
            float4 gv = *(const float4*)&gamma[g * 4];
            float4 bv = *(const float4*)&beta[g * 4];
            us4 ov;
            ov[0] = f2bf((bf2f(hv[0]) - mean) * rs * gv.x + bv.x);
            ov[1] = f2bf((bf2f(hv[1]) - mean) * rs * gv.y + bv.y);
            ov[2] = f2bf((bf2f(hv[2]) - mean) * rs * gv.z + bv.z);
            ov[3] = f2bf((bf2f(hv[3]) - mean) * rs * gv.w + bv.w);
            *(us4*)&hout[(size_t)m * 256 + g * 4] = ov;
        }
    } else {
        float part = 0.f;
        #pragma unroll
        for (int c4 = 0; c4 < 32; ++c4) {
            int g = jj * 32 + c4;
            us4 hv = *(const us4*)&Hr[((g ^ rx) << 2)];
            float4 gv = *(const float4*)&gamma[g * 4];
            float4 bv = *(const float4*)&beta[g * 4];
            float4 wv = *(const float4*)&wfin[g * 4];
            part += ((bf2f(hv[0]) - mean) * rs * gv.x + bv.x) * wv.x;
            part += ((bf2f(hv[1]) - mean) * rs * gv.y + bv.y) * wv.y;
            part += ((bf2f(hv[2]) - mean) * rs * gv.z + bv.z) * wv.z;
            part += ((bf2f(hv[3]) - mean) * rs * gv.w + bv.w) * wv.w;
        }
        part += __shfl_xor(part, 1);
        if (jj == 0) {
            float r = part + bfin[0];
            if (FIN == 1) { r = expf(r); r = r > 1.f ? r : 1.f; }
            fout[m] = r;
        }
    }
}

// ---------------------------------------------------------------------------
extern "C" void kernel_launch(void* const* d_in, const int* in_sizes, int n_in,
                              void* d_out, int out_size, void* d_ws, size_t ws_size,
                              hipStream_t stream) {
    const float* emb    = (const float*)d_in[0];
    const int*   dur    = (const int*)  d_in[1];
    const float* dp_w1  = (const float*)d_in[2];
    const float* dp_b1  = (const float*)d_in[3];
    const float* dp_g1  = (const float*)d_in[4];
    const float* dp_be1 = (const float*)d_in[5];
    const float* dp_w2  = (const float*)d_in[6];
    const float* dp_b2  = (const float*)d_in[7];
    const float* dp_g2  = (const float*)d_in[8];
    const float* dp_be2 = (const float*)d_in[9];
    const float* dp_w3  = (const float*)d_in[10];
    const float* dp_b3  = (const float*)d_in[11];
    const float* f0_w1  = (const float*)d_in[12];
    const float* f0_b1  = (const float*)d_in[13];
    const float* f0_g1  = (const float*)d_in[14];
    const float* f0_be1 = (const float*)d_in[15];
    const float* f0_w2  = (const float*)d_in[16];
    const float* f0_b2  = (const float*)d_in[17];

    float* up   = (float*)d_out;                       // (16, 4096, 512)
    float* pdur = up + (size_t)NB * NT * IND0;         // (16, 512)
    float* pf0  = pdur + NB * NS;                      // (16, 4096)

    char* ws = (char*)d_ws;
    int* cum             = (int*)(ws);                        // 32 KB
    int* idxarr          = (int*)(ws + 32768);                // 256 KB
    unsigned short* Wt1  = (unsigned short*)(ws + 294912);    // 256x1536 bf16
    unsigned short* Wt2  = (unsigned short*)(ws + 1081344);   // 256x768 bf16
    unsigned short* Wtf  = (unsigned short*)(ws + 1474560);   // 256x1536 bf16
    unsigned short* h1   = (unsigned short*)(ws + 2260992);   // 8192x256 bf16

    wprep_kernel<<<256, 256, 0, stream>>>(dp_w1, Wt1, 512);
    wprep_kernel<<<256, 256, 0, stream>>>(dp_w2, Wt2, 256);
    wprep_kernel<<<256, 256, 0, stream>>>(f0_w1, Wtf, 512);
    cumsum_kernel<<<NB, 64, 0, stream>>>(dur, cum);
    regulator_kernel<<<NB * NT / 2, 256, 0, stream>>>(emb, cum, up, idxarr);

    // duration predictor conv1: emb (f32 direct) -> h1 (bf16)
    conv_mfma<0, 512, 0, 9><<<NB * NS / 128, 256, 0, stream>>>(
        emb, nullptr, Wt1, dp_b1, dp_g1, dp_be1, h1, nullptr, nullptr, nullptr);
    // duration predictor conv2 + dur head: h1 (bf16 direct) -> pdur
    conv_mfma<2, 256, 1, 9><<<NB * NS / 128, 256, 0, stream>>>(
        h1, nullptr, Wt2, dp_b2, dp_g2, dp_be2, nullptr, dp_w3, dp_b3, pdur);
    // f0 conv + head: gather emb rows via idxarr -> pf0
    conv_mfma<1, 512, 2, 12><<<NB * NT / 128, 256, 0, stream>>>(
        emb, idxarr, Wtf, f0_b1, f0_g1, f0_be1, nullptr, f0_w2, f0_b2, pf0);
}

// Round 3
// 175.327 us; speedup vs baseline: 7.4893x; 1.5191x over previous
//
#include <hip/hip_runtime.h>
#include <math.h>

typedef __attribute__((ext_vector_type(8))) short short8;
typedef __attribute__((ext_vector_type(4))) float f32x4;
typedef __attribute__((ext_vector_type(4))) unsigned short us4;

constexpr int NB = 16, NS = 512, NT = 4096, IND0 = 512;

__device__ __forceinline__ unsigned short f2bf(float f) {
    __bf16 h = (__bf16)f;
    return __builtin_bit_cast(unsigned short, h);
}
__device__ __forceinline__ float bf2f(unsigned short h) {
    return __uint_as_float(((unsigned)h) << 16);
}

// ---------------------------------------------------------------------------
// Bulk f32 -> bf16 cast (emb -> emb_bf). n8 = elements/8.
__global__ void cast_bf16_kernel(const float* __restrict__ src,
                                 unsigned short* __restrict__ dst, int n8) {
    int i = blockIdx.x * blockDim.x + threadIdx.x;
    if (i >= n8) return;
    const float4* p = (const float4*)(src + (size_t)i * 8);
    float4 v0 = p[0], v1 = p[1];
    short8 o;
    o[0] = (short)f2bf(v0.x); o[1] = (short)f2bf(v0.y);
    o[2] = (short)f2bf(v0.z); o[3] = (short)f2bf(v0.w);
    o[4] = (short)f2bf(v1.x); o[5] = (short)f2bf(v1.y);
    o[6] = (short)f2bf(v1.z); o[7] = (short)f2bf(v1.w);
    *(short8*)(dst + (size_t)i * 8) = o;
}

// ---------------------------------------------------------------------------
// Weight prep: src (256, IND, 3) f32 -> bf16 fragments in exact MFMA B order:
// frag (st, w, nf, s): elem [l*8+e] = W[col = w*64+nf*16+(l&15)]
//                                      [k = st*64 + s*32 + (l>>4)*8 + e]
// with k = ko*IND + i  (i = k mod IND, ko = k div IND).
template<int IND>
__global__ void wprep_kernel(const float* __restrict__ src,
                             unsigned short* __restrict__ dst) {
    constexpr int K = 3 * IND;
    constexpr int LOGIND = (IND == 512) ? 9 : 8;
    int total = 256 * K;
    for (int idx = blockIdx.x * blockDim.x + threadIdx.x; idx < total;
         idx += gridDim.x * blockDim.x) {
        int e  = idx & 7;
        int l  = (idx >> 3) & 63;
        int s  = (idx >> 9) & 1;
        int nf = (idx >> 10) & 3;
        int w  = (idx >> 12) & 3;
        int st = idx >> 14;
        int k   = st * 64 + s * 32 + ((l >> 4) << 3) + e;
        int col = w * 64 + nf * 16 + (l & 15);
        int i   = k & (IND - 1);
        int ko  = k >> LOGIND;
        dst[idx] = f2bf(src[(col * IND + i) * 3 + ko]);
    }
}

// ---------------------------------------------------------------------------
// Per-batch cumsum + frame->phoneme index table. One block per batch.
__global__ void cumidx_kernel(const int* __restrict__ dur, int* __restrict__ idxarr) {
    __shared__ int cs[NS];
    __shared__ int wsum[4];
    int b = blockIdx.x, t = threadIdx.x, w = t >> 6, lane = t & 63;
    int v0 = dur[b * NS + t * 2], v1 = dur[b * NS + t * 2 + 1];
    int pair = v0 + v1;
    int incl = pair;
    for (int off = 1; off < 64; off <<= 1) {
        int n = __shfl_up(incl, off, 64);
        if (lane >= off) incl += n;
    }
    if (lane == 63) wsum[w] = incl;
    __syncthreads();
    int pre = 0;
    #pragma unroll
    for (int i = 0; i < 4; ++i) if (i < w) pre += wsum[i];
    incl += pre;
    cs[t * 2] = incl - v1;
    cs[t * 2 + 1] = incl;
    __syncthreads();
    int total = cs[NS - 1];
    for (int f = t; f < NT; f += 256) {
        int lo = 0, hi = NS;
        while (lo < hi) {
            int mid = (lo + hi) >> 1;
            if (cs[mid] <= f) lo = mid + 1; else hi = mid;
        }
        idxarr[b * NT + f] = (f < total) ? (lo < NS ? lo : NS - 1) : -1;
    }
}

// ---------------------------------------------------------------------------
// Fused conv1d(k=3,pad=1)+bias+relu+LayerNorm(256) [+1x1 head] as bf16 MFMA
// GEMM. Block: BM rows x 256 cols, 4 waves (wave tile BM x 64). BK=64.
// A: LDS double-buffer, 128B rows, 16B-chunk XOR swizzle (chunk ^= row&7).
// B: direct per-lane fragment loads from pre-swizzled global (no LDS).
// GATHER=1: rows via idxarr (f0 path) + fused f32 `up` write during ko==1.
// FIN: 0 = bf16 hout; 1 = dur head exp/max1; 2 = f0 head.
template<int GATHER, int BM, int IND, int FIN, int LOGSL>
__global__ __launch_bounds__(256, 2)
void conv_mfma(const unsigned short* __restrict__ src,
               const int* __restrict__ idxarr,
               const unsigned short* __restrict__ Bs,
               const float* __restrict__ bias, const float* __restrict__ gamma,
               const float* __restrict__ beta, unsigned short* __restrict__ hout,
               const float* __restrict__ wfin, const float* __restrict__ bfin,
               float* __restrict__ fout, float* __restrict__ up) {
    constexpr int K = 3 * IND;
    constexpr int NSTEP = K / 64;              // 24 or 12 (even)
    constexpr int LOGIND = (IND == 512) ? 9 : 8;
    constexpr int SL = 1 << LOGSL;
    constexpr int TPR = 256 / BM;              // threads per staged row
    constexpr int CH  = 8 / TPR;               // 16B chunks per thread
    constexpr int MF  = BM / 16;
    constexpr int BUFS = BM * 64;              // ushorts per A buffer

    __shared__ unsigned short smem[BM * 256];  // union: 2 A-bufs | H tile

    const int t = threadIdx.x;
    const int m0 = blockIdx.x * BM;
    const int w = t >> 6, l = t & 63, llo = l & 15, lhi = l >> 4;

    const int arow = t / TPR, sub = t % TPR;
    const int am = m0 + arow, ab = am >> LOGSL, as_ = am & (SL - 1);

    f32x4 acc[MF][4];
    #pragma unroll
    for (int i = 0; i < MF; ++i)
        #pragma unroll
        for (int j = 0; j < 4; ++j) acc[i][j] = (f32x4){0.f, 0.f, 0.f, 0.f};

    short8 a[CH];
    short8 b0[8], b1[8];

    auto stageA = [&](int st) {
        int ko = st >> (LOGIND - 6);
        int i0 = (st & ((1 << (LOGIND - 6)) - 1)) << 6;
        int tr = as_ + ko - 1;
        bool valid = (tr >= 0) && (tr < SL);
        long srow = 0;
        if (GATHER) {
            int ix = valid ? idxarr[(ab << LOGSL) + tr] : -1;
            valid = ix >= 0;
            srow = (long)ab * NS + (ix >= 0 ? ix : 0);
        } else {
            srow = (long)ab * SL + (valid ? tr : 0);
        }
        if (valid) {
            const unsigned short* p = src + srow * IND + i0 + sub * CH * 8;
            #pragma unroll
            for (int j = 0; j < CH; ++j) a[j] = *(const short8*)(p + j * 8);
        } else {
            #pragma unroll
            for (int j = 0; j < CH; ++j) a[j] = short8{0,0,0,0,0,0,0,0};
        }
    };
    auto dsWriteA = [&](int st) {
        int buf = (st & 1) * BUFS;
        #pragma unroll
        for (int j = 0; j < CH; ++j)
            *(short8*)&smem[buf + arow * 64 + (((sub * CH + j) ^ (arow & 7)) << 3)] = a[j];
        if (GATHER) {
            int ko = st >> (LOGIND - 6);
            if (ko == 1) {  // staged rows == up rows: fused output write
                int i0 = (st & ((1 << (LOGIND - 6)) - 1)) << 6;
                float* dstp = up + (size_t)am * IND0 + i0 + sub * CH * 8;
                #pragma unroll
                for (int j = 0; j < CH; ++j) {
                    f32x4 lo, hi;
                    #pragma unroll
                    for (int e = 0; e < 4; ++e) {
                        lo[e] = bf2f((unsigned short)a[j][e]);
                        hi[e] = bf2f((unsigned short)a[j][4 + e]);
                    }
                    *(f32x4*)(dstp + j * 8) = lo;
                    *(f32x4*)(dstp + j * 8 + 4) = hi;
                }
            }
        }
    };
    auto loadB = [&](int st, short8* b) {
        const unsigned short* base = Bs + ((size_t)(st * 4 + w) * 8) * 512 + l * 8;
        #pragma unroll
        for (int s = 0; s < 2; ++s)
            #pragma unroll
            for (int nf = 0; nf < 4; ++nf)
                b[s * 4 + nf] = *(const short8*)(base + (nf * 2 + s) * 512);
    };
    auto mfmaPhase = [&](int st, short8* bc) {
        int buf = (st & 1) * BUFS;
        #pragma unroll
        for (int s = 0; s < 2; ++s)
            #pragma unroll
            for (int mf = 0; mf < MF; ++mf) {
                short8 af = *(const short8*)&smem[buf + (mf * 16 + llo) * 64 +
                                                 ((((s << 2) | lhi) ^ (llo & 7)) << 3)];
                #pragma unroll
                for (int nf = 0; nf < 4; ++nf)
                    acc[mf][nf] = __builtin_amdgcn_mfma_f32_16x16x32_bf16(
                        af, bc[s * 4 + nf], acc[mf][nf], 0, 0, 0);
            }
    };

    // prologue
    stageA(0); loadB(0, b0);
    dsWriteA(0);
    stageA(1);
    __syncthreads();
    for (int st = 0; st < NSTEP; st += 2) {
        // even body: uses b0, prefetches b1
        dsWriteA(st + 1);
        if (st + 2 < NSTEP) stageA(st + 2);
        loadB(st + 1, b1);
        mfmaPhase(st, b0);
        __syncthreads();
        // odd body: uses b1, prefetches b0
        if (st + 2 < NSTEP) {
            dsWriteA(st + 2);
            if (st + 3 < NSTEP) stageA(st + 3);
            loadB(st + 2, b0);
        }
        mfmaPhase(st + 1, b1);
        __syncthreads();
    }

    // Epilogue: bias+relu -> H (XOR-swizzled [BM][256] bf16)
    unsigned short* H = smem;
    #pragma unroll
    for (int nf = 0; nf < 4; ++nf) {
        int col = w * 64 + nf * 16 + llo;
        float bv = bias[col];
        #pragma unroll
        for (int mf = 0; mf < MF; ++mf)
            #pragma unroll
            for (int r = 0; r < 4; ++r) {
                int row = mf * 16 + lhi * 4 + r;
                float v = acc[mf][nf][r] + bv;
                v = v > 0.f ? v : 0.f;
                H[row * 256 + ((((col >> 2) ^ (row & 15)) << 2) | (col & 3))] = f2bf(v);
            }
    }
    __syncthreads();

    // LayerNorm over 256 channels: Q threads per row
    constexpr int Q = 256 / BM;
    constexpr int NG = 64 / Q;   // 4-col groups per thread
    int row = t / Q, jj = t % Q;
    const unsigned short* Hr = H + row * 256;
    int rx = row & 15;
    float sum = 0.f, sq = 0.f;
    #pragma unroll
    for (int c4 = 0; c4 < NG; ++c4) {
        int g = jj * NG + c4;
        us4 hv = *(const us4*)&Hr[(g ^ rx) << 2];
        #pragma unroll
        for (int e = 0; e < 4; ++e) { float f = bf2f(hv[e]); sum += f; sq += f * f; }
    }
    #pragma unroll
    for (int off = Q / 2; off >= 1; off >>= 1) {
        sum += __shfl_xor(sum, off);
        sq  += __shfl_xor(sq, off);
    }
    float mean = sum * (1.f / 256.f);
    float var  = sq * (1.f / 256.f) - mean * mean;
    float rs   = rsqrtf(var + 1e-5f);
    int m = m0 + row;

    if (FIN == 0) {
        #pragma unroll
        for (int c4 = 0; c4 < NG; ++c4) {
            int g = jj * NG + c4;
            us4 hv = *(const us4*)&Hr[(g ^ rx) << 2];
            float4 gv = *(const float4*)&gamma[g * 4];
            float4 bv = *(const float4*)&beta[g * 4];
            us4 ov;
            ov[0] = f2bf((bf2f(hv[0]) - mean) * rs * gv.x + bv.x);
            ov[1] = f2bf((bf2f(hv[1]) - mean) * rs * gv.y + bv.y);
            ov[2] = f2bf((bf2f(hv[2]) - mean) * rs * gv.z + bv.z);
            ov[3] = f2bf((bf2f(hv[3]) - mean) * rs * gv.w + bv.w);
            *(us4*)&hout[(size_t)m * 256 + g * 4] = ov;
        }
    } else {
        float part = 0.f;
        #pragma unroll
        for (int c4 = 0; c4 < NG; ++c4) {
            int g = jj * NG + c4;
            us4 hv = *(const us4*)&Hr[(g ^ rx) << 2];
            float4 gv = *(const float4*)&gamma[g * 4];
            float4 bv = *(const float4*)&beta[g * 4];
            float4 wv = *(const float4*)&wfin[g * 4];
            part += ((bf2f(hv[0]) - mean) * rs * gv.x + bv.x) * wv.x;
            part += ((bf2f(hv[1]) - mean) * rs * gv.y + bv.y) * wv.y;
            part += ((bf2f(hv[2]) - mean) * rs * gv.z + bv.z) * wv.z;
            part += ((bf2f(hv[3]) - mean) * rs * gv.w + bv.w) * wv.w;
        }
        #pragma unroll
        for (int off = Q / 2; off >= 1; off >>= 1) part += __shfl_xor(part, off);
        if (jj == 0) {
            float r = part + bfin[0];
            if (FIN == 1) { r = expf(r); r = r > 1.f ? r : 1.f; }
            fout[m] = r;
        }
    }
}

// ---------------------------------------------------------------------------
extern "C" void kernel_launch(void* const* d_in, const int* in_sizes, int n_in,
                              void* d_out, int out_size, void* d_ws, size_t ws_size,
                              hipStream_t stream) {
    const float* emb    = (const float*)d_in[0];
    const int*   dur    = (const int*)  d_in[1];
    const float* dp_w1  = (const float*)d_in[2];
    const float* dp_b1  = (const float*)d_in[3];
    const float* dp_g1  = (const float*)d_in[4];
    const float* dp_be1 = (const float*)d_in[5];
    const float* dp_w2  = (const float*)d_in[6];
    const float* dp_b2  = (const float*)d_in[7];
    const float* dp_g2  = (const float*)d_in[8];
    const float* dp_be2 = (const float*)d_in[9];
    const float* dp_w3  = (const float*)d_in[10];
    const float* dp_b3  = (const float*)d_in[11];
    const float* f0_w1  = (const float*)d_in[12];
    const float* f0_b1  = (const float*)d_in[13];
    const float* f0_g1  = (const float*)d_in[14];
    const float* f0_be1 = (const float*)d_in[15];
    const float* f0_w2  = (const float*)d_in[16];
    const float* f0_b2  = (const float*)d_in[17];

    float* up   = (float*)d_out;                       // (16, 4096, 512)
    float* pdur = up + (size_t)NB * NT * IND0;         // (16, 512)
    float* pf0  = pdur + NB * NS;                      // (16, 4096)

    char* ws = (char*)d_ws;
    int*            idxarr = (int*)(ws);                          // 256 KB
    unsigned short* Bs1    = (unsigned short*)(ws + 262144);      // 768 KB
    unsigned short* Bs2    = (unsigned short*)(ws + 1048576);     // 384 KB
    unsigned short* Bsf    = (unsigned short*)(ws + 1441792);     // 768 KB
    unsigned short* h1     = (unsigned short*)(ws + 2228224);     // 4 MB
    unsigned short* emb_bf = (unsigned short*)(ws + 6422528);     // 8 MB

    cast_bf16_kernel<<<2048, 256, 0, stream>>>(emb, emb_bf, NB * NS * IND0 / 8);
    wprep_kernel<512><<<768, 256, 0, stream>>>(dp_w1, Bs1);
    wprep_kernel<256><<<384, 256, 0, stream>>>(dp_w2, Bs2);
    wprep_kernel<512><<<768, 256, 0, stream>>>(f0_w1, Bsf);
    cumidx_kernel<<<NB, 256, 0, stream>>>(dur, idxarr);

    // duration predictor conv1: emb_bf -> h1 (bf16)
    conv_mfma<0, 64, 512, 0, 9><<<NB * NS / 64, 256, 0, stream>>>(
        emb_bf, nullptr, Bs1, dp_b1, dp_g1, dp_be1, h1, nullptr, nullptr, nullptr, nullptr);
    // duration predictor conv2 + dur head: h1 -> pdur
    conv_mfma<0, 64, 256, 1, 9><<<NB * NS / 64, 256, 0, stream>>>(
        h1, nullptr, Bs2, dp_b2, dp_g2, dp_be2, nullptr, dp_w3, dp_b3, pdur, nullptr);
    // f0 conv + head: gather emb_bf rows via idxarr -> pf0, fused `up` write
    conv_mfma<1, 128, 512, 2, 12><<<NB * NT / 128, 256, 0, stream>>>(
        emb_bf, idxarr, Bsf, f0_b1, f0_g1, f0_be1, nullptr, f0_w2, f0_b2, pf0, up);
}